// Round 10
// baseline (89.148 us; speedup 1.0000x reference)
//
#include <hip/hip_runtime.h>
#include <math.h>

#define BLOCK 256
#define SPLIT 2            // threads cooperating per pixel-pair
#define PPT   2            // pixels per thread
#define MAX_KV_LDS 1024

__device__ __forceinline__ float rcp1(float x)  { return __builtin_amdgcn_rcpf(x); }
__device__ __forceinline__ float rsq1(float x)  { return __builtin_amdgcn_rsqf(x); }
__device__ __forceinline__ float sqrt1(float x) { return __builtin_amdgcn_sqrtf(x); }

#define ACONST 4.4721439e-3f      // acos(1 - 1e-5)
#define PIF    3.14159265358979f
#define PImA   3.1371205f         // pi - ACONST
#define TWOPI  6.28318530717959f
#define INV2PI 0.15915494309189535f
#define CR2MIN 1.6e-9f            // |cr| < 4e-5  <=>  |K_SIGN*cr| < 4 (tanh unsat)

// Rare fix (|K*cr|<4): replace ideal sign(cr)*theta by reference's
// tanh(K*cr)*clamp(theta).  (Main loop counts only the exact -2pi*W.)
__device__ __forceinline__ float rare_fix(float cr, float dt)
{
    float ac = fabsf(cr), ad = fabsf(dt);
    float mn = fminf(ac, ad), mx = fmaxf(ac, ad);
    float q  = mn * rcp1(mx);
    float s2 = q * q;
    float r = fmaf(fmaf(fmaf(fmaf(0.0208351f, s2, -0.0851330f), s2,
                  0.1801410f), s2, -0.3302995f), s2, 0.9998660f) * q;
    r = (ac > ad) ? (1.57079632679f - r) : r;
    float theta = (dt < 0.0f) ? (PIF - r) : r;
    float thc = __builtin_amdgcn_fmed3f(theta, ACONST, PImA);  // EPS clamp
    float t  = cr * 100000.0f;
    float s  = t * t;
    float nm = t * fmaf(s + 105.0f, s, 945.0f);
    float qd = fmaf(fmaf(15.0f, s, 420.0f), s, 945.0f);
    float th = __builtin_amdgcn_fmed3f(nm * rcp1(qd), -1.0f, 1.0f);
    float scr = (cr >= 0.0f) ? 1.0f : -1.0f;
    return fmaf(th, thc, -scr * theta);
}

// Full-precision per-edge term for the cold fallback path.
__device__ __forceinline__ float edge_term_s(float cr, float dt)
{
    float n2 = fmaf(cr, cr, dt * dt);
    float co = dt * rsq1(n2);
    co = __builtin_amdgcn_fmed3f(co, -0.99999f, 0.99999f);
    float y = fabsf(co);
    float p = fmaf(fmaf(fmaf(-0.0187293f, y, 0.0742610f), y, -0.2121144f),
                   y, 1.5707288f);
    float a = sqrt1(1.0f - y) * p;
    a = (co >= 0.0f) ? a : (PIF - a);
    float t  = cr * 100000.0f;
    float s  = t * t;
    float nm = t * fmaf(s + 105.0f, s, 945.0f);
    float qd = fmaf(fmaf(15.0f, s, 420.0f), s, 945.0f);
    float th = __builtin_amdgcn_fmed3f(nm * rcp1(qd), -1.0f, 1.0f);
    return th * a;
}

__global__ __launch_bounds__(BLOCK, 4)
void contour_mask_kernel(const float2* __restrict__ contour,
                         const int* __restrict__ size_ptr,
                         float* __restrict__ out,
                         int out_size, int in0_elems)
{
    __shared__ float2 verts[65];

    const int size = *size_ptr;                // wave-uniform scalar load
    const int S2   = size * size;

    const int tid  = threadIdx.x;
    const int PIX_PER_BLOCK = (BLOCK / SPLIT) * PPT;     // 256
    const int base = blockIdx.x * PIX_PER_BLOCK;

    // hot path requires: kv==64, pow2 size, S2 multiple of 256, full block
    const bool kv64  = ((long long)in0_elems * S2 == 128LL * out_size);
    const bool pow2  = (size & (size - 1)) == 0;
    const bool whole = ((S2 & (PIX_PER_BLOCK - 1)) == 0) &&
                       (base + PIX_PER_BLOCK <= out_size);
    const bool hot = kv64 && pow2 && whole && size >= 2;

    const int lg  = 31 - __clz(size);          // log2(size), pow2 path
    const int bn0 = hot ? (base >> (2 * lg)) : (base / S2);

    if (hot) {
        if (tid < 64)
            verts[tid] = contour[(size_t)bn0 * 64 + tid];
        if (tid == 0)
            verts[64] = contour[(size_t)bn0 * 64];   // wraparound duplicate
    }
    __syncthreads();

    const float inv_size = 1.0f / (float)size;

    if (hot) {
        const int rem = base & (S2 - 1);       // multiple of 256
        const int pi0 = rem >> lg;
        const int seg = tid & (SPLIT - 1);
        const int t   = tid & ~1;              // even local pixel offset
        const int pjA = t & (size - 1);        // even
        const int piA = pi0 + (t >> lg);
        // pair shares the row: pjB = pjA+1 (< size since pjA even)

        const float mx  = (float)piA * inv_size;      // mesh ch0 = i/size
        const float myA = (float)pjA * inv_size;      // mesh ch1 = j/size

        const int k0 = seg * 32;
        float2 v = verts[k0];
        float dx  = v.x - mx;
        float dyA = v.y - myA;
        float dyB = dyA - inv_size;
        bool dygtA = dyA > 0.0f;
        bool dygtB = dyB > 0.0f;
        float SA = 0.0f, SB = 0.0f;            // accumulates -2pi*W
        bool anyA = false, anyB = false;       // tanh-unsaturated flags
        bool multiA = false, multiB = false;   // >=2 flagged edges (rare^2)
        int  kA = 0, kB = 0;                   // last flagged edge index

        #pragma unroll
        for (int k = 0; k < 32; ++k) {
            float2 vn = verts[k0 + k + 1];     // imm-offset ds_read_b64
            float rx  = vn.x - mx;             // shared by both pixels
            float ryA = vn.y - myA;
            float ryB = ryA - inv_size;

            { // ---- pixel A: ray-crossing count + flag bookkeeping ----
                float cr = fmaf(dyA, rx, -(dx * ryA));
                bool rygt = ryA > 0.0f;
                float dS = 0.0f;
                dS = (!dygtA && rygt && cr < 0.0f) ? -TWOPI : dS;   // up
                dS = ( dygtA && !rygt && cr > 0.0f) ?  TWOPI : dS;  // down
                SA += dS;
                bool flag = cr * cr < CR2MIN;
                kA = flag ? k : kA;            // v_cndmask
                multiA = multiA || (flag && anyA);   // scalar mask ops
                anyA = anyA || flag;
                dyA = ryA; dygtA = rygt;
            }
            { // ---- pixel B ----
                float cr = fmaf(dyB, rx, -(dx * ryB));
                bool rygt = ryB > 0.0f;
                float dS = 0.0f;
                dS = (!dygtB && rygt && cr < 0.0f) ? -TWOPI : dS;
                dS = ( dygtB && !rygt && cr > 0.0f) ?  TWOPI : dS;
                SB += dS;
                bool flag = cr * cr < CR2MIN;
                kB = flag ? k : kB;
                multiB = multiB || (flag && anyB);
                anyB = anyB || flag;
                dyB = ryB; dygtB = rygt;
            }
            dx = rx;
        }

        // common rare case: exactly one flagged edge -> direct fix, no rescan
        if (anyA && !multiA) {
            float2 va = verts[k0 + kA], vb = verts[k0 + kA + 1];
            float ddx = va.x - mx, ddy = va.y - myA;
            float rrx = vb.x - mx, rry = vb.y - myA;
            float cr = fmaf(ddy, rrx, -(ddx * rry));
            float dt = fmaf(ddx, rrx, ddy * rry);
            SA += rare_fix(cr, dt);
        }
        if (anyB && !multiB) {
            const float myB = myA + inv_size;
            float2 va = verts[k0 + kB], vb = verts[k0 + kB + 1];
            float ddx = va.x - mx, ddy = va.y - myB;
            float rrx = vb.x - mx, rry = vb.y - myB;
            float cr = fmaf(ddy, rrx, -(ddx * rry));
            float dt = fmaf(ddx, rrx, ddy * rry);
            SB += rare_fix(cr, dt);
        }
        // ultra-rare: >=2 flagged edges for one pixel -> full rescan
        if (__ballot(multiA || multiB)) {
            float2 v0 = verts[k0];
            float dx2 = v0.x - mx;
            float dA  = v0.y - myA;
            float dB  = dA - inv_size;
            for (int k = 0; k < 32; ++k) {
                float2 vn = verts[k0 + k + 1];
                float rx  = vn.x - mx;
                float rA  = vn.y - myA;
                float rB  = rA - inv_size;
                if (multiA) {
                    float cr = fmaf(dA, rx, -(dx2 * rA));
                    if (cr * cr < CR2MIN)
                        SA += rare_fix(cr, fmaf(dx2, rx, dA * rA));
                }
                if (multiB) {
                    float cr = fmaf(dB, rx, -(dx2 * rB));
                    if (cr * cr < CR2MIN)
                        SB += rare_fix(cr, fmaf(dx2, rx, dB * rB));
                }
                dx2 = rx; dA = rA; dB = rB;
            }
        }

        SA += __shfl_xor(SA, 1, 64);           // combine the 2 segments
        SB += __shfl_xor(SB, 1, 64);

        if (seg == 0) {
            float2 res;
            res.x = fminf(fabsf(SA) * INV2PI, 1.0f);
            res.y = fminf(fabsf(SB) * INV2PI, 1.0f);
            *(float2*)(out + base + t) = res;  // coalesced 8B store
        }
        return;
    }

    // COLD fallback: generic sizes/kv, global-memory vertex reads
    const int bn_total = out_size / S2;
    const int kv       = in0_elems / (bn_total * 2);
    const int seg = tid & (SPLIT - 1);
    const int q   = (kv + SPLIT - 1) / SPLIT;
    const int k0  = min(seg * q, kv);
    const int k1  = min(k0 + q, kv);

    #pragma unroll
    for (int px = 0; px < PPT; ++px) {
        const int pixel = base + (tid / SPLIT) * PPT + px;
        float a = 0.0f;
        if (pixel < out_size && k0 < k1) {
            const int bn = pixel / S2;
            const int p  = pixel - bn * S2;
            const int pi = p / size;
            const int pj = p - pi * size;
            const float mxs = pi * inv_size;
            const float mys = pj * inv_size;
            const float2* vsrc = contour + (size_t)bn * kv;
            float2 v = vsrc[k0];
            float dx = v.x - mxs, dy = v.y - mys;
            for (int k = k0; k < k1; ++k) {
                int kn = k + 1; if (kn == kv) kn = 0;
                float2 vn = vsrc[kn];
                float rx = vn.x - mxs, ry = vn.y - mys;
                float cr = fmaf(dy, rx, -(dx * ry));
                float dt = fmaf(dx, rx, dy * ry);
                a += edge_term_s(cr, dt);
                dx = rx; dy = ry;
            }
        }
        a += __shfl_xor(a, 1, 64);
        if (pixel < out_size && seg == 0)
            out[pixel] = fminf(fabsf(a) * INV2PI, 1.0f);
    }
}

extern "C" void kernel_launch(void* const* d_in, const int* in_sizes, int n_in,
                              void* d_out, int out_size, void* d_ws, size_t ws_size,
                              hipStream_t stream)
{
    const float2* contour  = (const float2*)d_in[0];
    const int*    size_ptr = (const int*)d_in[1];
    float*        out      = (float*)d_out;

    const int PIX_PER_BLOCK = (BLOCK / SPLIT) * PPT;   // 256 pixels per block
    const int blocks = (out_size + PIX_PER_BLOCK - 1) / PIX_PER_BLOCK;
    contour_mask_kernel<<<blocks, BLOCK, 0, stream>>>(
        contour, size_ptr, out, out_size, in_sizes[0]);
}

// Round 11
// 67.119 us; speedup vs baseline: 1.3282x; 1.3282x over previous
//
#include <hip/hip_runtime.h>
#include <math.h>

#define BLOCK 256
#define SPLIT 2            // threads cooperating per pixel-pair
#define PPT   2            // pixels per thread

__device__ __forceinline__ float rcp1(float x)  { return __builtin_amdgcn_rcpf(x); }
__device__ __forceinline__ float rsq1(float x)  { return __builtin_amdgcn_rsqf(x); }
__device__ __forceinline__ float sqrt1(float x) { return __builtin_amdgcn_sqrtf(x); }

#define ACONST 4.4721439e-3f      // acos(1 - 1e-5)
#define PIF    3.14159265358979f
#define PImA   3.1371205f         // pi - ACONST
#define TWOPI  6.28318530717959f
#define INV2PI 0.15915494309189535f
#define CR2MIN 1.6e-9f            // |cr| < 4e-5  <=>  |K_SIGN*cr| < 4 (tanh unsat)

// Rare fix (|K*cr|<4): replace ideal sign(cr)*theta by reference's
// tanh(K*cr)*clamp(theta).  (Main loop counts only the exact -2pi*W.)
__device__ __forceinline__ float rare_fix(float cr, float dt)
{
    float ac = fabsf(cr), ad = fabsf(dt);
    float mn = fminf(ac, ad), mx = fmaxf(ac, ad);
    float q  = mn * rcp1(mx);
    float s2 = q * q;
    float r = fmaf(fmaf(fmaf(fmaf(0.0208351f, s2, -0.0851330f), s2,
                  0.1801410f), s2, -0.3302995f), s2, 0.9998660f) * q;
    r = (ac > ad) ? (1.57079632679f - r) : r;
    float theta = (dt < 0.0f) ? (PIF - r) : r;
    float thc = __builtin_amdgcn_fmed3f(theta, ACONST, PImA);  // EPS clamp
    float t  = cr * 100000.0f;
    float s  = t * t;
    float nm = t * fmaf(s + 105.0f, s, 945.0f);
    float qd = fmaf(fmaf(15.0f, s, 420.0f), s, 945.0f);
    float th = __builtin_amdgcn_fmed3f(nm * rcp1(qd), -1.0f, 1.0f);
    float scr = (cr >= 0.0f) ? 1.0f : -1.0f;
    return fmaf(th, thc, -scr * theta);
}

// Full-precision per-edge term for the cold fallback path.
__device__ __forceinline__ float edge_term_s(float cr, float dt)
{
    float n2 = fmaf(cr, cr, dt * dt);
    float co = dt * rsq1(n2);
    co = __builtin_amdgcn_fmed3f(co, -0.99999f, 0.99999f);
    float y = fabsf(co);
    float p = fmaf(fmaf(fmaf(-0.0187293f, y, 0.0742610f), y, -0.2121144f),
                   y, 1.5707288f);
    float a = sqrt1(1.0f - y) * p;
    a = (co >= 0.0f) ? a : (PIF - a);
    float t  = cr * 100000.0f;
    float s  = t * t;
    float nm = t * fmaf(s + 105.0f, s, 945.0f);
    float qd = fmaf(fmaf(15.0f, s, 420.0f), s, 945.0f);
    float th = __builtin_amdgcn_fmed3f(nm * rcp1(qd), -1.0f, 1.0f);
    return th * a;
}

__global__ __launch_bounds__(BLOCK, 4)
void contour_mask_kernel(const float2* __restrict__ contour,
                         const int* __restrict__ size_ptr,
                         float* __restrict__ out,
                         int out_size, int in0_elems)
{
    __shared__ float2 verts[65];

    const int size = *size_ptr;                // wave-uniform scalar load
    const int S2   = size * size;

    const int tid  = threadIdx.x;
    const int PIX_PER_BLOCK = (BLOCK / SPLIT) * PPT;     // 256
    const int base = blockIdx.x * PIX_PER_BLOCK;

    const int bn0 = base / S2;                 // uniform divide (once/wave)
    const int rem = base - bn0 * S2;
    const bool one_image = (rem + PIX_PER_BLOCK <= S2) &&
                           (base + PIX_PER_BLOCK <= out_size);
    // kv == 64 test without a divide: kv = in0_elems*S2/(2*out_size)
    const bool kv64 = ((long long)in0_elems * S2 == 128LL * out_size);
    const bool use_lds = kv64 && one_image;

    if (use_lds) {
        if (tid < 64)
            verts[tid] = contour[(size_t)bn0 * 64 + tid];
        if (tid == 0)
            verts[64] = contour[(size_t)bn0 * 64];   // wraparound duplicate
    }
    __syncthreads();

    const float inv_size = 1.0f / (float)size;

    // HOT: kv==64 (32 edges/seg), vertices preloaded to REGISTERS
    if (use_lds && (size & 1) == 0) {
        int pi0, pj0;
        if ((size & (size - 1)) == 0) {        // pow2 size: shifts not divides
            const int lg = 31 - __clz(size);
            pi0 = rem >> lg;
            pj0 = rem & (size - 1);
        } else {
            pi0 = rem / size;
            pj0 = rem - pi0 * size;
        }
        const int seg = tid & (SPLIT - 1);
        const int t   = tid & ~1;              // even local pixel offset

        int pjA = pj0 + t, piA = pi0;
        while (pjA >= size) { pjA -= size; ++piA; }   // pjA stays even
        // pair shares the row: piB==piA, pjB==pjA+1

        const float mx  = (float)piA * inv_size;      // mesh ch0 = i/size
        const float myA = (float)pjA * inv_size;      // mesh ch1 = j/size

        const int k0 = seg * 32;

        // ---- preload the segment's 33 vertices into registers ----
        // 17 independent ds_read_b128s, one wait; main loop is then pure ALU
        // (tests the LDS-latency-floor hypothesis; ~66 VGPRs, budget 128)
        float2 vloc[33];
        #pragma unroll
        for (int k = 0; k < 33; ++k)
            vloc[k] = verts[k0 + k];

        float dx  = vloc[0].x - mx;
        float dyA = vloc[0].y - myA;
        float dyB = dyA - inv_size;
        bool dygtA = dyA > 0.0f;
        bool dygtB = dyB > 0.0f;
        float SA = 0.0f, SB = 0.0f;            // accumulates -2pi*W
        bool anyA = false, anyB = false;       // tanh-unsaturated flags

        #pragma unroll
        for (int k = 0; k < 32; ++k) {
            float rx  = vloc[k + 1].x - mx;    // register-resident vertex
            float ryA = vloc[k + 1].y - myA;
            float ryB = ryA - inv_size;

            { // ---- pixel A: ray-crossing count only ----
                float cr = fmaf(dyA, rx, -(dx * ryA));
                bool rygt = ryA > 0.0f;
                float dS = 0.0f;
                dS = (!dygtA && rygt && cr < 0.0f) ? -TWOPI : dS;   // up
                dS = ( dygtA && !rygt && cr > 0.0f) ?  TWOPI : dS;  // down
                SA += dS;
                anyA = anyA || (cr * cr < CR2MIN);
                dyA = ryA; dygtA = rygt;
            }
            { // ---- pixel B ----
                float cr = fmaf(dyB, rx, -(dx * ryB));
                bool rygt = ryB > 0.0f;
                float dS = 0.0f;
                dS = (!dygtB && rygt && cr < 0.0f) ? -TWOPI : dS;
                dS = ( dygtB && !rygt && cr > 0.0f) ?  TWOPI : dS;
                SB += dS;
                anyB = anyB || (cr * cr < CR2MIN);
                dyB = ryB; dygtB = rygt;
            }
            dx = rx;
        }

        // rare pass: pixels near an edge line where tanh is unsaturated
        // (reads LDS; runtime loop keeps code small, latency irrelevant here)
        if (anyA || anyB) {                    // execz-skipped when none
            float2 v0 = verts[k0];
            float dx2  = v0.x - mx;
            float dA   = v0.y - myA;
            float dB   = dA - inv_size;
            #pragma unroll 1
            for (int k = 0; k < 32; ++k) {
                float2 vn = verts[k0 + k + 1];
                float rx  = vn.x - mx;
                float rA  = vn.y - myA;
                float rB  = rA - inv_size;
                if (anyA) {
                    float cr = fmaf(dA, rx, -(dx2 * rA));
                    if (cr * cr < CR2MIN) {
                        float dt = fmaf(dx2, rx, dA * rA);
                        SA += rare_fix(cr, dt);
                    }
                }
                if (anyB) {
                    float cr = fmaf(dB, rx, -(dx2 * rB));
                    if (cr * cr < CR2MIN) {
                        float dt = fmaf(dx2, rx, dB * rB);
                        SB += rare_fix(cr, dt);
                    }
                }
                dx2 = rx; dA = rA; dB = rB;
            }
        }

        SA += __shfl_xor(SA, 1, 64);           // combine the 2 segments
        SB += __shfl_xor(SB, 1, 64);

        if (seg == 0) {
            float2 res;
            res.x = fminf(fabsf(SA) * INV2PI, 1.0f);
            res.y = fminf(fabsf(SB) * INV2PI, 1.0f);
            *(float2*)(out + base + t) = res;  // coalesced 8B store
        }
        return;
    }

    // COLD fallback: generic sizes/kv, global-memory vertex reads
    const int bn_total = out_size / S2;
    const int kv       = in0_elems / (bn_total * 2);
    const int seg = tid & (SPLIT - 1);
    const int q   = (kv + SPLIT - 1) / SPLIT;
    const int k0  = min(seg * q, kv);
    const int k1  = min(k0 + q, kv);

    #pragma unroll
    for (int px = 0; px < PPT; ++px) {
        const int pixel = base + (tid / SPLIT) * PPT + px;
        float a = 0.0f;
        if (pixel < out_size && k0 < k1) {
            const int bn = pixel / S2;
            const int p  = pixel - bn * S2;
            const int pi = p / size;
            const int pj = p - pi * size;
            const float mxs = pi * inv_size;
            const float mys = pj * inv_size;
            const float2* vsrc = contour + (size_t)bn * kv;
            float2 v = vsrc[k0];
            float dx = v.x - mxs, dy = v.y - mys;
            for (int k = k0; k < k1; ++k) {
                int kn = k + 1; if (kn == kv) kn = 0;
                float2 vn = vsrc[kn];
                float rx = vn.x - mxs, ry = vn.y - mys;
                float cr = fmaf(dy, rx, -(dx * ry));
                float dt = fmaf(dx, rx, dy * ry);
                a += edge_term_s(cr, dt);
                dx = rx; dy = ry;
            }
        }
        a += __shfl_xor(a, 1, 64);
        if (pixel < out_size && seg == 0)
            out[pixel] = fminf(fabsf(a) * INV2PI, 1.0f);
    }
}

extern "C" void kernel_launch(void* const* d_in, const int* in_sizes, int n_in,
                              void* d_out, int out_size, void* d_ws, size_t ws_size,
                              hipStream_t stream)
{
    const float2* contour  = (const float2*)d_in[0];
    const int*    size_ptr = (const int*)d_in[1];
    float*        out      = (float*)d_out;

    const int PIX_PER_BLOCK = (BLOCK / SPLIT) * PPT;   // 256 pixels per block
    const int blocks = (out_size + PIX_PER_BLOCK - 1) / PIX_PER_BLOCK;
    contour_mask_kernel<<<blocks, BLOCK, 0, stream>>>(
        contour, size_ptr, out, out_size, in_sizes[0]);
}